// Round 4
// baseline (19026.437 us; speedup 1.0000x reference)
//
#include <hip/hip_runtime.h>
#include <math.h>

#define BSZ 512
#define NV  30
#define NT  24
#define SS  768          // state row stride (x: 0..249, m: 250..749, 750..767 = zero pad)
#define WLD 1280         // packed weight/z col count: sw 0..511, mem 512..1023, sv 1024..1279
#define WROWS 780        // 750 + 30 one-hot rows (layer 1 only; zero for others)
#define ZP  (BSZ * WLD)  // zbuf plane stride
#define NGROUP 16        // batch groups of 32 rows
#define GBLK 32          // blocks per group (16 N-tiles x 2 K-splits)

// ---------------- init: zero state + barriers ----------------
__global__ void init_kernel(float* S0, float* S1, unsigned* bar) {
    int i = blockIdx.x * blockDim.x + threadIdx.x;
    int st = gridDim.x * blockDim.x;
    for (int k = i; k < BSZ * SS; k += st) { S0[k] = 0.f; S1[k] = 0.f; }
    if (i < NGROUP * 32) bar[i] = 0u;
}

// ---------------- prepack: concat+pad weights and biases ----------------
__global__ void prepack_kernel(const float* __restrict__ w1_sw, const float* __restrict__ w1_mem,
                               const float* __restrict__ w1_sv,
                               const float* __restrict__ w_sw,  const float* __restrict__ w_mem,
                               const float* __restrict__ w_sv,
                               const float* __restrict__ b1_sw, const float* __restrict__ b1_mem,
                               const float* __restrict__ b1_sv,
                               const float* __restrict__ b_sw,  const float* __restrict__ b_mem,
                               const float* __restrict__ b_sv,
                               float* __restrict__ Wcat, float* __restrict__ Bcat)
{
    const int total = 6 * WROWS * WLD;
    int i = blockIdx.x * blockDim.x + threadIdx.x;
    int st = gridDim.x * blockDim.x;
    for (int idx = i; idx < total; idx += st) {
        int l = idx / (WROWS * WLD);
        int rem = idx - l * (WROWS * WLD);
        int k = rem / WLD;
        int n = rem - k * WLD;
        float v = 0.f;
        const int rows = (l == 0) ? 780 : 750;
        if (k < rows) {
            if (n < 512) {
                if (n < 500) v = (l == 0) ? w1_sw[k * 500 + n]
                                          : w_sw[(size_t)(l - 1) * 750 * 500 + k * 500 + n];
            } else if (n < 1024) {
                int j = n - 512;
                if (j < 500) v = (l == 0) ? w1_mem[k * 500 + j]
                                          : w_mem[(size_t)(l - 1) * 750 * 500 + k * 500 + j];
            } else {
                int j = n - 1024;
                if (j < 250) v = (l == 0) ? w1_sv[k * 250 + j]
                                          : w_sv[(size_t)(l - 1) * 750 * 250 + k * 250 + j];
            }
        }
        Wcat[idx] = v;
    }
    for (int idx = i; idx < 6 * WLD; idx += st) {
        int l = idx / WLD;
        int n = idx - l * WLD;
        float v = 0.f;
        if (n < 512)       { if (n < 500)        v = (l == 0) ? b1_sw[n]  : b_sw[(l - 1) * 500 + n]; }
        else if (n < 1024) { int j = n - 512;  if (j < 500) v = (l == 0) ? b1_mem[j] : b_mem[(l - 1) * 500 + j]; }
        else               { int j = n - 1024; if (j < 250) v = (l == 0) ? b1_sv[j]  : b_sv[(l - 1) * 250 + j]; }
        Bcat[idx] = v;
    }
}

// ---------------- group barrier (device-scope, generation-based) ----------------
__device__ __forceinline__ void group_barrier(unsigned* bar, unsigned nblk) {
    __syncthreads();
    if (threadIdx.x == 0) {
        __threadfence();  // push this block's global writes device-visible
        unsigned gen = __hip_atomic_load(bar + 1, __ATOMIC_RELAXED, __HIP_MEMORY_SCOPE_AGENT);
        unsigned prev = __hip_atomic_fetch_add(bar, 1u, __ATOMIC_ACQ_REL, __HIP_MEMORY_SCOPE_AGENT);
        if (prev == nblk - 1u) {
            __hip_atomic_store(bar, 0u, __ATOMIC_RELAXED, __HIP_MEMORY_SCOPE_AGENT);
            __hip_atomic_store(bar + 1, gen + 1u, __ATOMIC_RELEASE, __HIP_MEMORY_SCOPE_AGENT);
        } else {
            while (__hip_atomic_load(bar + 1, __ATOMIC_ACQUIRE, __HIP_MEMORY_SCOPE_AGENT) == gen)
                __builtin_amdgcn_s_sleep(1);
        }
    }
    __syncthreads();
}

// ---------------- persistent recurrent kernel ----------------
// grid = 512 blocks x 128 threads. block -> (group, ksp, tile):
//   group = gid>>5 (32 rows of batch), sub = gid&31, ksp = sub>>4 (K half), tile = sub&15 (80 cols)
// per gate: GEMM partial (32x80, K=384) -> barrier -> fused epilogue -> barrier.
__launch_bounds__(128)
__global__ void recurrent_kernel(const int* __restrict__ letters,
                                 const float* __restrict__ Wcat, const float* __restrict__ Bcat,
                                 float* __restrict__ S0, float* __restrict__ S1,
                                 float* __restrict__ zbuf, unsigned* __restrict__ barls)
{
    const int tid   = threadIdx.x;
    const int gid   = blockIdx.x;
    const int group = gid >> 5;
    const int sub   = gid & 31;
    const int ksp   = sub >> 4;
    const int tile  = sub & 15;
    const int m0    = group * 32;
    const int n0    = tile * 80;
    const int kbeg  = ksp * 384;
    unsigned* bar   = barls + group * 32;

    __shared__ float As[2][32][36];
    __shared__ float Bs[2][32][84];

    const int tx = tid & 15, ty = tid >> 4;   // compute: cols {tx+16j}, rows ty*4+i
    const int kl = tid & 31, rl = tid >> 5;   // A stage: k=kl, rows rl+4i
    const int kb = tid & 31, cb = tid >> 5;   // B stage: k=kb, float4 col-groups cb+4j

    float* cur = S0;
    float* nxt = S1;

    for (int t = 0; t < NT; t++) {
        for (int l = 0; l < 6; l++) {
            const float* __restrict__ Wc = Wcat + (size_t)l * WROWS * WLD;

            // ---- GEMM phase: acc[4][5] = cur[m0:m0+32, kbeg:kbeg+384] @ Wc[kbeg:.., n0:n0+80]
            {
                float acc[4][5];
                #pragma unroll
                for (int i = 0; i < 4; i++)
                    #pragma unroll
                    for (int j = 0; j < 5; j++) acc[i][j] = 0.f;

                float ar[8]; float4 br[5];
                {
                    const float* ap = cur + (size_t)(m0 + rl) * SS + kbeg + kl;
                    #pragma unroll
                    for (int i = 0; i < 8; i++) ar[i] = ap[(size_t)(4 * i) * SS];
                    const float* bp = Wc + (size_t)(kbeg + kb) * WLD + n0 + cb * 4;
                    #pragma unroll
                    for (int j = 0; j < 5; j++) br[j] = *(const float4*)(bp + 16 * j);
                    #pragma unroll
                    for (int i = 0; i < 8; i++) As[0][kl][rl + 4 * i] = ar[i];
                    #pragma unroll
                    for (int j = 0; j < 5; j++) *(float4*)&Bs[0][kb][(cb + 4 * j) * 4] = br[j];
                }
                __syncthreads();

                int buf = 0;
                #pragma unroll 1
                for (int kt = 0; kt < 12; kt++) {
                    if (kt < 11) {
                        const int k0 = kbeg + (kt + 1) * 32;
                        const float* ap = cur + (size_t)(m0 + rl) * SS + k0 + kl;
                        #pragma unroll
                        for (int i = 0; i < 8; i++) ar[i] = ap[(size_t)(4 * i) * SS];
                        const float* bp = Wc + (size_t)(k0 + kb) * WLD + n0 + cb * 4;
                        #pragma unroll
                        for (int j = 0; j < 5; j++) br[j] = *(const float4*)(bp + 16 * j);
                    }
                    #pragma unroll
                    for (int kk = 0; kk < 32; kk++) {
                        float4 av = *(const float4*)&As[buf][kk][ty * 4];
                        const float a4[4] = {av.x, av.y, av.z, av.w};
                        #pragma unroll
                        for (int j = 0; j < 5; j++) {
                            const float b = Bs[buf][kk][tx + 16 * j];
                            #pragma unroll
                            for (int i = 0; i < 4; i++)
                                acc[i][j] = fmaf(a4[i], b, acc[i][j]);
                        }
                    }
                    if (kt < 11) {
                        #pragma unroll
                        for (int i = 0; i < 8; i++) As[buf ^ 1][kl][rl + 4 * i] = ar[i];
                        #pragma unroll
                        for (int j = 0; j < 5; j++) *(float4*)&Bs[buf ^ 1][kb][(cb + 4 * j) * 4] = br[j];
                        __syncthreads();
                        buf ^= 1;
                    }
                }
                float* zo = zbuf + (size_t)ksp * ZP + (size_t)m0 * WLD + n0;
                #pragma unroll
                for (int i = 0; i < 4; i++) {
                    float* zr = zo + (size_t)(ty * 4 + i) * WLD;
                    #pragma unroll
                    for (int j = 0; j < 5; j++) zr[tx + 16 * j] = acc[i][j];
                }
            }

            group_barrier(bar, GBLK);

            // ---- epilogue phase: 32 rows x 750 state cols over 32 blocks x 128 thr
            {
                const float* Bc = Bcat + l * WLD;
                for (int idx = sub * 128 + tid; idx < 32 * 750; idx += GBLK * 128) {
                    const int r = idx / 750;
                    const int n = idx - r * 750;
                    const int b = m0 + r;
                    const float* z0 = zbuf + (size_t)b * WLD;
                    const float* z1 = z0 + ZP;
                    const float* oh = nullptr;
                    if (l == 0) oh = Wcat + (size_t)(750 + letters[b * NT + t]) * WLD;
                    if (n < 250) {
                        float zx = z0[1024 + n] + z1[1024 + n] + Bc[1024 + n];
                        if (oh) zx += oh[1024 + n];
                        nxt[(size_t)b * SS + n] = tanhf(zx);
                    } else {
                        const int j = n - 250;
                        float zs = z0[j] + z1[j] + Bc[j];
                        float zm = z0[512 + j] + z1[512 + j] + Bc[512 + j];
                        if (oh) { zs += oh[j]; zm += oh[512 + j]; }
                        const float s = 1.f / (1.f + expf(-zs));
                        const float mo = cur[(size_t)b * SS + 250 + j];
                        nxt[(size_t)b * SS + 250 + j] = mo * s + tanhf(zm) * (1.f - s);
                    }
                }
            }

            group_barrier(bar, GBLK);
            { float* tmp = cur; cur = nxt; nxt = tmp; }
        }
    }
}

// ---------------- head GEMM: Y = tanh(X @ W + b) ----------------
__launch_bounds__(128)
__global__ void head_gemm(const float* __restrict__ X, int ldx, int K,
                          const float* __restrict__ W, const float* __restrict__ bias,
                          float* __restrict__ Y, int N)
{
    const int tid = threadIdx.x;
    const int m0 = blockIdx.y * 32;
    const int n0 = blockIdx.x * 64;

    __shared__ float As[2][32][36];
    __shared__ float Bs[2][32][68];

    const int tx = tid & 15, ty = tid >> 4;
    const int kl = tid & 31, rl = tid >> 5;
    const int cl = tid & 63, kg = tid >> 6;
    const bool cok = (n0 + cl) < N;

    float acc[4][4] = {{0.f}};
    float ar[8], br[16];

    {
        const float* a = X + (size_t)(m0 + rl) * ldx + kl;
        #pragma unroll
        for (int i = 0; i < 8; i++) ar[i] = a[(size_t)(4 * i) * ldx];
        #pragma unroll
        for (int i = 0; i < 16; i++)
            br[i] = cok ? W[(size_t)(kg + 2 * i) * N + n0 + cl] : 0.f;
        #pragma unroll
        for (int i = 0; i < 8; i++) As[0][kl][rl + 4 * i] = ar[i];
        #pragma unroll
        for (int i = 0; i < 16; i++) Bs[0][kg + 2 * i][cl] = br[i];
    }
    __syncthreads();

    int buf = 0;
    const int NK = (K + 31) / 32;
    #pragma unroll 1
    for (int kt = 0; kt < NK; kt++) {
        const bool more = (kt + 1 < NK);
        if (more) {
            const int k0 = (kt + 1) * 32;
            const bool ka = (k0 + kl) < K;
            const float* a = X + (size_t)(m0 + rl) * ldx + k0 + kl;
            #pragma unroll
            for (int i = 0; i < 8; i++) ar[i] = ka ? a[(size_t)(4 * i) * ldx] : 0.f;
            #pragma unroll
            for (int i = 0; i < 16; i++) {
                const int kk = k0 + kg + 2 * i;
                br[i] = (cok && kk < K) ? W[(size_t)kk * N + n0 + cl] : 0.f;
            }
        }
        #pragma unroll
        for (int kk = 0; kk < 32; kk++) {
            float4 av = *(const float4*)&As[buf][kk][ty * 4];
            float4 bv = *(const float4*)&Bs[buf][kk][tx * 4];
            const float aa[4] = {av.x, av.y, av.z, av.w};
            const float bb[4] = {bv.x, bv.y, bv.z, bv.w};
            #pragma unroll
            for (int i = 0; i < 4; i++)
                #pragma unroll
                for (int j = 0; j < 4; j++)
                    acc[i][j] = fmaf(aa[i], bb[j], acc[i][j]);
        }
        if (more) {
            #pragma unroll
            for (int i = 0; i < 8; i++) As[buf ^ 1][kl][rl + 4 * i] = ar[i];
            #pragma unroll
            for (int i = 0; i < 16; i++) Bs[buf ^ 1][kg + 2 * i][cl] = br[i];
            __syncthreads();
            buf ^= 1;
        }
    }

    #pragma unroll
    for (int i = 0; i < 4; i++) {
        const int b = m0 + ty * 4 + i;
        #pragma unroll
        for (int j = 0; j < 4; j++) {
            const int n = n0 + tx * 4 + j;
            if (n < N) Y[(size_t)b * N + n] = tanhf(acc[i][j] + bias[n]);
        }
    }
}

// ---------------- final: logits (K=100, N=30) + softmax ----------------
__global__ void head_final(const float* __restrict__ Y4, const float* __restrict__ W,
                           const float* __restrict__ bias, float* __restrict__ out)
{
    const int row = blockIdx.x;
    __shared__ float y[100];
    __shared__ float z[NV];
    for (int k = threadIdx.x; k < 100; k += 64) y[k] = Y4[row * 100 + k];
    __syncthreads();
    const int n = threadIdx.x;
    if (n < NV) {
        float acc = bias[n];
        for (int k = 0; k < 100; k++) acc = fmaf(y[k], W[k * NV + n], acc);
        z[n] = acc;
    }
    __syncthreads();
    if (n < NV) {
        float mx = -1e30f;
        for (int i = 0; i < NV; i++) mx = fmaxf(mx, z[i]);
        float sum = 0.f;
        for (int i = 0; i < NV; i++) sum += expf(z[i] - mx);
        out[row * NV + n] = expf(z[n] - mx) / sum;
    }
}

extern "C" void kernel_launch(void* const* d_in, const int* in_sizes, int n_in,
                              void* d_out, int out_size, void* d_ws, size_t ws_size,
                              hipStream_t stream)
{
    const int*   letters = (const int*)  d_in[0];
    const float* w1_sv   = (const float*)d_in[1];
    const float* b1_sv   = (const float*)d_in[2];
    const float* w1_mem  = (const float*)d_in[3];
    const float* b1_mem  = (const float*)d_in[4];
    const float* w1_sw   = (const float*)d_in[5];
    const float* b1_sw   = (const float*)d_in[6];
    const float* w_sv    = (const float*)d_in[7];
    const float* b_sv    = (const float*)d_in[8];
    const float* w_mem   = (const float*)d_in[9];
    const float* b_mem   = (const float*)d_in[10];
    const float* w_sw    = (const float*)d_in[11];
    const float* b_sw    = (const float*)d_in[12];
    const float* wp1 = (const float*)d_in[13]; const float* bp1 = (const float*)d_in[14];
    const float* wp2 = (const float*)d_in[15]; const float* bp2 = (const float*)d_in[16];
    const float* wp3 = (const float*)d_in[17]; const float* bp3 = (const float*)d_in[18];
    const float* wp4 = (const float*)d_in[19]; const float* bp4 = (const float*)d_in[20];
    const float* wp5 = (const float*)d_in[21]; const float* bp5 = (const float*)d_in[22];

    float* S0   = (float*)d_ws;                       // 512*768
    float* S1   = S0 + (size_t)BSZ * SS;              // 512*768
    float* Zb   = S1 + (size_t)BSZ * SS;              // 2*512*1280
    float* Wcat = Zb + 2 * (size_t)ZP;                // 6*780*1280
    float* Bcat = Wcat + (size_t)6 * WROWS * WLD;     // 6*1280
    unsigned* bar = (unsigned*)(Bcat + 6 * WLD);      // 16*32 u32
    // head buffers alias zbuf (free after recurrence)
    float* Y1 = Zb;
    float* Y2 = Y1 + (size_t)BSZ * 450;
    float* Y3 = Y2 + (size_t)BSZ * 300;
    float* Y4 = Y3 + (size_t)BSZ * 200;

    init_kernel<<<512, 256, 0, stream>>>(S0, S1, bar);
    prepack_kernel<<<1024, 256, 0, stream>>>(w1_sw, w1_mem, w1_sv, w_sw, w_mem, w_sv,
                                             b1_sw, b1_mem, b1_sv, b_sw, b_mem, b_sv,
                                             Wcat, Bcat);
    recurrent_kernel<<<NGROUP * GBLK, 128, 0, stream>>>(letters, Wcat, Bcat, S0, S1, Zb, bar);

    head_gemm<<<dim3(8, 16), 128, 0, stream>>>(S0, SS, 750, wp1, bp1, Y1, 450);
    head_gemm<<<dim3(5, 16), 128, 0, stream>>>(Y1, 450, 450, wp2, bp2, Y2, 300);
    head_gemm<<<dim3(4, 16), 128, 0, stream>>>(Y2, 300, 300, wp3, bp3, Y3, 200);
    head_gemm<<<dim3(2, 16), 128, 0, stream>>>(Y3, 200, 200, wp4, bp4, Y4, 100);
    head_final<<<BSZ, 64, 0, stream>>>(Y4, wp5, bp5, (float*)d_out);
}

// Round 5
// 8023.779 us; speedup vs baseline: 2.3713x; 2.3713x over previous
//
#include <hip/hip_runtime.h>
#include <math.h>

#define BSZ 512
#define NV  30
#define NT  24
#define SS  768          // state row stride (x: 0..249, m: 250..749, 750..767 = zero pad)
#define WLD 1280         // packed cols: sw 0..511, mem 512..1023, sv 1024..1279
#define WROWS 780        // 750 + 30 one-hot rows (layer 1; zero for others)
#define ZP  (BSZ * WLD)  // zbuf plane stride
#define NGROUP 16
#define GBLK 32          // blocks per group (16 N-tiles x 2 K-splits)

// ---- cache-bypassing (device-coherent) scalar access: no L2 invalidation ----
__device__ __forceinline__ float ldg_dev(const float* p) {
    return __hip_atomic_load(p, __ATOMIC_RELAXED, __HIP_MEMORY_SCOPE_AGENT);
}
__device__ __forceinline__ void stg_dev(float* p, float v) {
    __hip_atomic_store(p, v, __ATOMIC_RELAXED, __HIP_MEMORY_SCOPE_AGENT);
}

// ---------------- init: zero state + barrier counters ----------------
__global__ void init_kernel(float* S0, float* S1, unsigned* ctr) {
    int i = blockIdx.x * blockDim.x + threadIdx.x;
    int st = gridDim.x * blockDim.x;
    for (int k = i; k < BSZ * SS; k += st) { S0[k] = 0.f; S1[k] = 0.f; }
    if (i < NGROUP * 16) ctr[i] = 0u;   // one counter per group, 64B apart
}

// ---------------- prepack: concat+pad weights and biases ----------------
__global__ void prepack_kernel(const float* __restrict__ w1_sw, const float* __restrict__ w1_mem,
                               const float* __restrict__ w1_sv,
                               const float* __restrict__ w_sw,  const float* __restrict__ w_mem,
                               const float* __restrict__ w_sv,
                               const float* __restrict__ b1_sw, const float* __restrict__ b1_mem,
                               const float* __restrict__ b1_sv,
                               const float* __restrict__ b_sw,  const float* __restrict__ b_mem,
                               const float* __restrict__ b_sv,
                               float* __restrict__ Wcat, float* __restrict__ Bcat)
{
    const int total = 6 * WROWS * WLD;
    int i = blockIdx.x * blockDim.x + threadIdx.x;
    int st = gridDim.x * blockDim.x;
    for (int idx = i; idx < total; idx += st) {
        int l = idx / (WROWS * WLD);
        int rem = idx - l * (WROWS * WLD);
        int k = rem / WLD;
        int n = rem - k * WLD;
        float v = 0.f;
        const int rows = (l == 0) ? 780 : 750;
        if (k < rows) {
            if (n < 512) {
                if (n < 500) v = (l == 0) ? w1_sw[k * 500 + n]
                                          : w_sw[(size_t)(l - 1) * 750 * 500 + k * 500 + n];
            } else if (n < 1024) {
                int j = n - 512;
                if (j < 500) v = (l == 0) ? w1_mem[k * 500 + j]
                                          : w_mem[(size_t)(l - 1) * 750 * 500 + k * 500 + j];
            } else {
                int j = n - 1024;
                if (j < 250) v = (l == 0) ? w1_sv[k * 250 + j]
                                          : w_sv[(size_t)(l - 1) * 750 * 250 + k * 250 + j];
            }
        }
        Wcat[idx] = v;
    }
    for (int idx = i; idx < 6 * WLD; idx += st) {
        int l = idx / WLD;
        int n = idx - l * WLD;
        float v = 0.f;
        if (n < 512)       { if (n < 500)        v = (l == 0) ? b1_sw[n]  : b_sw[(l - 1) * 500 + n]; }
        else if (n < 1024) { int j = n - 512;  if (j < 500) v = (l == 0) ? b1_mem[j] : b_mem[(l - 1) * 500 + j]; }
        else               { int j = n - 1024; if (j < 250) v = (l == 0) ? b1_sv[j]  : b_sv[(l - 1) * 250 + j]; }
        Bcat[idx] = v;
    }
}

// ---------------- fence-free group barrier (monotonic counter) ----------------
__device__ __forceinline__ void group_barrier(unsigned* ctr, unsigned target) {
    __syncthreads();
    if (threadIdx.x == 0) {
        __atomic_signal_fence(__ATOMIC_SEQ_CST);
        __builtin_amdgcn_s_waitcnt(0);   // drain this block's write-through stores
        __hip_atomic_fetch_add(ctr, 1u, __ATOMIC_RELAXED, __HIP_MEMORY_SCOPE_AGENT);
        while (__hip_atomic_load(ctr, __ATOMIC_RELAXED, __HIP_MEMORY_SCOPE_AGENT) < target)
            __builtin_amdgcn_s_sleep(2);
        __atomic_signal_fence(__ATOMIC_SEQ_CST);
    }
    __syncthreads();
}

// ---------------- persistent recurrent kernel ----------------
// grid = 512 x 128. block -> (group = gid>>5, sub = gid&31), sub -> (ksp = sub>>4, tile = sub&15).
// Weights/bias/letters: cached (immutable, L2-resident). State/zbuf: bypass atomics.
__launch_bounds__(128)
__global__ void recurrent_kernel(const int* __restrict__ letters,
                                 const float* __restrict__ Wcat, const float* __restrict__ Bcat,
                                 float* __restrict__ S0, float* __restrict__ S1,
                                 float* __restrict__ zbuf, unsigned* __restrict__ ctrs)
{
    const int tid   = threadIdx.x;
    const int gid   = blockIdx.x;
    const int group = gid >> 5;
    const int sub   = gid & 31;
    const int ksp   = sub >> 4;
    const int tile  = sub & 15;
    const int m0    = group * 32;
    const int n0    = tile * 80;
    const int kbeg  = ksp * 384;
    unsigned* ctr   = ctrs + group * 16;
    unsigned round  = 0;

    __shared__ float As[2][32][36];
    __shared__ float Bs[2][32][84];

    const int tx = tid & 15, ty = tid >> 4;   // compute: cols {tx+16j}, rows ty*4+i
    const int kl = tid & 31, rl = tid >> 5;   // A stage: k=kl, rows rl+4i
    const int kb = tid & 31, cb = tid >> 5;   // B stage: k=kb, float4 col-groups cb+4j

    float* cur = S0;
    float* nxt = S1;

    for (int t = 0; t < NT; t++) {
        for (int l = 0; l < 6; l++) {
            const float* __restrict__ Wc = Wcat + (size_t)l * WROWS * WLD;

            // ---- GEMM phase: acc[4][5] = cur[m0:+32, kbeg:+384] @ Wc[kbeg:+384, n0:+80]
            {
                float acc[4][5];
                #pragma unroll
                for (int i = 0; i < 4; i++)
                    #pragma unroll
                    for (int j = 0; j < 5; j++) acc[i][j] = 0.f;

                float ar[8]; float4 br[5];
                {
                    const float* ap = cur + (size_t)(m0 + rl) * SS + kbeg + kl;
                    #pragma unroll
                    for (int i = 0; i < 8; i++) ar[i] = ldg_dev(ap + (size_t)(4 * i) * SS);
                    const float* bp = Wc + (size_t)(kbeg + kb) * WLD + n0 + cb * 4;
                    #pragma unroll
                    for (int j = 0; j < 5; j++) br[j] = *(const float4*)(bp + 16 * j);
                    #pragma unroll
                    for (int i = 0; i < 8; i++) As[0][kl][rl + 4 * i] = ar[i];
                    #pragma unroll
                    for (int j = 0; j < 5; j++) *(float4*)&Bs[0][kb][(cb + 4 * j) * 4] = br[j];
                }
                __syncthreads();

                int buf = 0;
                #pragma unroll 1
                for (int kt = 0; kt < 12; kt++) {
                    if (kt < 11) {
                        const int k0 = kbeg + (kt + 1) * 32;
                        const float* ap = cur + (size_t)(m0 + rl) * SS + k0 + kl;
                        #pragma unroll
                        for (int i = 0; i < 8; i++) ar[i] = ldg_dev(ap + (size_t)(4 * i) * SS);
                        const float* bp = Wc + (size_t)(k0 + kb) * WLD + n0 + cb * 4;
                        #pragma unroll
                        for (int j = 0; j < 5; j++) br[j] = *(const float4*)(bp + 16 * j);
                    }
                    #pragma unroll
                    for (int kk = 0; kk < 32; kk++) {
                        float4 av = *(const float4*)&As[buf][kk][ty * 4];
                        const float a4[4] = {av.x, av.y, av.z, av.w};
                        #pragma unroll
                        for (int j = 0; j < 5; j++) {
                            const float b = Bs[buf][kk][tx + 16 * j];
                            #pragma unroll
                            for (int i = 0; i < 4; i++)
                                acc[i][j] = fmaf(a4[i], b, acc[i][j]);
                        }
                    }
                    if (kt < 11) {
                        #pragma unroll
                        for (int i = 0; i < 8; i++) As[buf ^ 1][kl][rl + 4 * i] = ar[i];
                        #pragma unroll
                        for (int j = 0; j < 5; j++) *(float4*)&Bs[buf ^ 1][kb][(cb + 4 * j) * 4] = br[j];
                        __syncthreads();
                        buf ^= 1;
                    }
                }
                float* zo = zbuf + (size_t)ksp * ZP + (size_t)m0 * WLD + n0;
                #pragma unroll
                for (int i = 0; i < 4; i++) {
                    float* zr = zo + (size_t)(ty * 4 + i) * WLD;
                    #pragma unroll
                    for (int j = 0; j < 5; j++) stg_dev(zr + tx + 16 * j, acc[i][j]);
                }
            }

            round++;
            group_barrier(ctr, GBLK * round);

            // ---- epilogue phase: 32 rows x 750 cols spread over the group's 32 blocks
            {
                const float* Bc = Bcat + l * WLD;
                for (int idx = sub * 128 + tid; idx < 32 * 750; idx += GBLK * 128) {
                    const int r = idx / 750;
                    const int n = idx - r * 750;
                    const int b = m0 + r;
                    const float* z0 = zbuf + (size_t)b * WLD;
                    const float* z1 = z0 + ZP;
                    const float* oh = nullptr;
                    if (l == 0) oh = Wcat + (size_t)(750 + letters[b * NT + t]) * WLD;
                    if (n < 250) {
                        float zx = ldg_dev(z0 + 1024 + n) + ldg_dev(z1 + 1024 + n) + Bc[1024 + n];
                        if (oh) zx += oh[1024 + n];
                        stg_dev(nxt + (size_t)b * SS + n, tanhf(zx));
                    } else {
                        const int j = n - 250;
                        float zs = ldg_dev(z0 + j) + ldg_dev(z1 + j) + Bc[j];
                        float zm = ldg_dev(z0 + 512 + j) + ldg_dev(z1 + 512 + j) + Bc[512 + j];
                        if (oh) { zs += oh[j]; zm += oh[512 + j]; }
                        const float s = 1.f / (1.f + expf(-zs));
                        const float mo = ldg_dev(cur + (size_t)b * SS + 250 + j);
                        stg_dev(nxt + (size_t)b * SS + 250 + j, mo * s + tanhf(zm) * (1.f - s));
                    }
                }
            }

            round++;
            group_barrier(ctr, GBLK * round);
            { float* tmp = cur; cur = nxt; nxt = tmp; }
        }
    }
}

// ---------------- head GEMM: Y = tanh(X @ W + b) ----------------
__launch_bounds__(128)
__global__ void head_gemm(const float* __restrict__ X, int ldx, int K,
                          const float* __restrict__ W, const float* __restrict__ bias,
                          float* __restrict__ Y, int N)
{
    const int tid = threadIdx.x;
    const int m0 = blockIdx.y * 32;
    const int n0 = blockIdx.x * 64;

    __shared__ float As[2][32][36];
    __shared__ float Bs[2][32][68];

    const int tx = tid & 15, ty = tid >> 4;
    const int kl = tid & 31, rl = tid >> 5;
    const int cl = tid & 63, kg = tid >> 6;
    const bool cok = (n0 + cl) < N;

    float acc[4][4] = {{0.f}};
    float ar[8], br[16];

    {
        const float* a = X + (size_t)(m0 + rl) * ldx + kl;
        #pragma unroll
        for (int i = 0; i < 8; i++) ar[i] = a[(size_t)(4 * i) * ldx];
        #pragma unroll
        for (int i = 0; i < 16; i++)
            br[i] = cok ? W[(size_t)(kg + 2 * i) * N + n0 + cl] : 0.f;
        #pragma unroll
        for (int i = 0; i < 8; i++) As[0][kl][rl + 4 * i] = ar[i];
        #pragma unroll
        for (int i = 0; i < 16; i++) Bs[0][kg + 2 * i][cl] = br[i];
    }
    __syncthreads();

    int buf = 0;
    const int NK = (K + 31) / 32;
    #pragma unroll 1
    for (int kt = 0; kt < NK; kt++) {
        const bool more = (kt + 1 < NK);
        if (more) {
            const int k0 = (kt + 1) * 32;
            const bool ka = (k0 + kl) < K;
            const float* a = X + (size_t)(m0 + rl) * ldx + k0 + kl;
            #pragma unroll
            for (int i = 0; i < 8; i++) ar[i] = ka ? a[(size_t)(4 * i) * ldx] : 0.f;
            #pragma unroll
            for (int i = 0; i < 16; i++) {
                const int kk = k0 + kg + 2 * i;
                br[i] = (cok && kk < K) ? W[(size_t)kk * N + n0 + cl] : 0.f;
            }
        }
        #pragma unroll
        for (int kk = 0; kk < 32; kk++) {
            float4 av = *(const float4*)&As[buf][kk][ty * 4];
            float4 bv = *(const float4*)&Bs[buf][kk][tx * 4];
            const float aa[4] = {av.x, av.y, av.z, av.w};
            const float bb[4] = {bv.x, bv.y, bv.z, bv.w};
            #pragma unroll
            for (int i = 0; i < 4; i++)
                #pragma unroll
                for (int j = 0; j < 4; j++)
                    acc[i][j] = fmaf(aa[i], bb[j], acc[i][j]);
        }
        if (more) {
            #pragma unroll
            for (int i = 0; i < 8; i++) As[buf ^ 1][kl][rl + 4 * i] = ar[i];
            #pragma unroll
            for (int i = 0; i < 16; i++) Bs[buf ^ 1][kg + 2 * i][cl] = br[i];
            __syncthreads();
            buf ^= 1;
        }
    }

    #pragma unroll
    for (int i = 0; i < 4; i++) {
        const int b = m0 + ty * 4 + i;
        #pragma unroll
        for (int j = 0; j < 4; j++) {
            const int n = n0 + tx * 4 + j;
            if (n < N) Y[(size_t)b * N + n] = tanhf(acc[i][j] + bias[n]);
        }
    }
}

// ---------------- final: logits (K=100, N=30) + softmax ----------------
__global__ void head_final(const float* __restrict__ Y4, const float* __restrict__ W,
                           const float* __restrict__ bias, float* __restrict__ out)
{
    const int row = blockIdx.x;
    __shared__ float y[100];
    __shared__ float z[NV];
    for (int k = threadIdx.x; k < 100; k += 64) y[k] = Y4[row * 100 + k];
    __syncthreads();
    const int n = threadIdx.x;
    if (n < NV) {
        float acc = bias[n];
        for (int k = 0; k < 100; k++) acc = fmaf(y[k], W[k * NV + n], acc);
        z[n] = acc;
    }
    __syncthreads();
    if (n < NV) {
        float mx = -1e30f;
        for (int i = 0; i < NV; i++) mx = fmaxf(mx, z[i]);
        float sum = 0.f;
        for (int i = 0; i < NV; i++) sum += expf(z[i] - mx);
        out[row * NV + n] = expf(z[n] - mx) / sum;
    }
}

extern "C" void kernel_launch(void* const* d_in, const int* in_sizes, int n_in,
                              void* d_out, int out_size, void* d_ws, size_t ws_size,
                              hipStream_t stream)
{
    const int*   letters = (const int*)  d_in[0];
    const float* w1_sv   = (const float*)d_in[1];
    const float* b1_sv   = (const float*)d_in[2];
    const float* w1_mem  = (const float*)d_in[3];
    const float* b1_mem  = (const float*)d_in[4];
    const float* w1_sw   = (const float*)d_in[5];
    const float* b1_sw   = (const float*)d_in[6];
    const float* w_sv    = (const float*)d_in[7];
    const float* b_sv    = (const float*)d_in[8];
    const float* w_mem   = (const float*)d_in[9];
    const float* b_mem   = (const float*)d_in[10];
    const float* w_sw    = (const float*)d_in[11];
    const float* b_sw    = (const float*)d_in[12];
    const float* wp1 = (const float*)d_in[13]; const float* bp1 = (const float*)d_in[14];
    const float* wp2 = (const float*)d_in[15]; const float* bp2 = (const float*)d_in[16];
    const float* wp3 = (const float*)d_in[17]; const float* bp3 = (const float*)d_in[18];
    const float* wp4 = (const float*)d_in[19]; const float* bp4 = (const float*)d_in[20];
    const float* wp5 = (const float*)d_in[21]; const float* bp5 = (const float*)d_in[22];

    float* S0   = (float*)d_ws;                       // 512*768
    float* S1   = S0 + (size_t)BSZ * SS;              // 512*768
    float* Zb   = S1 + (size_t)BSZ * SS;              // 2*512*1280
    float* Wcat = Zb + 2 * (size_t)ZP;                // 6*780*1280
    float* Bcat = Wcat + (size_t)6 * WROWS * WLD;     // 6*1280
    unsigned* ctrs = (unsigned*)(Bcat + 6 * WLD);     // 16 groups * 16 u32 (64B apart)
    float* Y1 = Zb;                                   // head aliases zbuf
    float* Y2 = Y1 + (size_t)BSZ * 450;
    float* Y3 = Y2 + (size_t)BSZ * 300;
    float* Y4 = Y3 + (size_t)BSZ * 200;

    init_kernel<<<512, 256, 0, stream>>>(S0, S1, ctrs);
    prepack_kernel<<<1024, 256, 0, stream>>>(w1_sw, w1_mem, w1_sv, w_sw, w_mem, w_sv,
                                             b1_sw, b1_mem, b1_sv, b_sw, b_mem, b_sv,
                                             Wcat, Bcat);
    recurrent_kernel<<<NGROUP * GBLK, 128, 0, stream>>>(letters, Wcat, Bcat, S0, S1, Zb, ctrs);

    head_gemm<<<dim3(8, 16), 128, 0, stream>>>(S0, SS, 750, wp1, bp1, Y1, 450);
    head_gemm<<<dim3(5, 16), 128, 0, stream>>>(Y1, 450, 450, wp2, bp2, Y2, 300);
    head_gemm<<<dim3(4, 16), 128, 0, stream>>>(Y2, 300, 300, wp3, bp3, Y3, 200);
    head_gemm<<<dim3(2, 16), 128, 0, stream>>>(Y3, 200, 200, wp4, bp4, Y4, 100);
    head_final<<<BSZ, 64, 0, stream>>>(Y4, wp5, bp5, (float*)d_out);
}